// Round 2
// baseline (242.607 us; speedup 1.0000x reference)
//
#include <hip/hip_runtime.h>
#include <math.h>

// Single-query MHA, algebraically collapsed:
//   s[l,h] = x_l . p_h         (p_h = Wk_h^T q_h / sqrt(D); k-bias shift cancels in softmax)
//   z_h    = sum_l softmax(s)_lh * x_l
//   attn   = Wv z + bv ; out = Wo attn + bo
// All fp32. No max-subtraction needed: |s| ~ N(0,1), max ~ 5 << 88 (fp32 exp range).
//
// v6 retry (attn_fused5): prior round failed at the container level (infra),
// no kernel verdict. Same design: head-pair-per-wave, P in REGISTERS (32
// VGPR/wave), x streamed HBM->LDS via global_load_lds (16B) double-buffered,
// ONE barrier per 8-row tile. Score + z-accumulate fused per row. Packed
// 2-head 64-lane butterfly reduce: 6 shfl + 1 share, single exp.
// LDS 64.3 KB (2 blocks/CU), ~100 VGPR under __launch_bounds__(512,2).

#define L_SEQ   32768
#define E_DIM   1024
#define NHEAD   8
#define HDIM    128
#define TILE_R  8
#define WAVES_M 8            // 512 threads

// direct HBM->LDS, 16B per lane; gptr is PER-LANE, ldsptr is wave-uniform base
#define GLD16(gp, lp)                                                   \
  __builtin_amdgcn_global_load_lds(                                     \
      (const __attribute__((address_space(1))) void*)(gp),              \
      (__attribute__((address_space(3))) void*)(lp), 16, 0, 0)

// ---------------- q = Wq x0 + bq : wave-per-output GEMV ----------------
__global__ __launch_bounds__(256) void proj_q(
    const float* __restrict__ W, const float* __restrict__ bias,
    const float* __restrict__ x, float* __restrict__ q)
{
  const int t = threadIdx.x, wave = t >> 6, lane = t & 63;
  const int o = blockIdx.x * 4 + wave;
  const float4* Wr = (const float4*)(W + (size_t)o * E_DIM);
  const float4* xr = (const float4*)x;   // row 0 of x
  float a = 0.f;
#pragma unroll
  for (int k = 0; k < 4; ++k) {
    float4 wv = Wr[lane + 64 * k];
    float4 xv = xr[lane + 64 * k];
    a += wv.x * xv.x + wv.y * xv.y + wv.z * xv.z + wv.w * xv.w;
  }
#pragma unroll
  for (int m = 1; m < 64; m <<= 1) a += __shfl_xor(a, m, 64);
  if (lane == 0) q[o] = a + bias[o];
}

// ---------------- P_T[h][e] = (1/sqrt(D)) sum_d q[h*128+d] * Wk[h*128+d][e] ----------------
// 8-way d-split per block (short 16-load chains), LDS combine.
__global__ __launch_bounds__(256) void make_p(
    const float* __restrict__ W, const float* __restrict__ q,
    float* __restrict__ P_T)
{
  __shared__ __align__(16) float4 ps[8][32];
  const int t  = threadIdx.x;
  const int h  = blockIdx.y;           // head
  const int ec = blockIdx.x;           // e-chunk of 128
  const int eg = t & 31;               // float4 slot within chunk
  const int dg = t >> 5;               // d-group of 16
  const float* Wb = W + ((size_t)E_DIM + h * HDIM + dg * 16) * E_DIM + ec * 128 + eg * 4;
  const float* qh = q + h * HDIM + dg * 16;
  float4 a = make_float4(0.f, 0.f, 0.f, 0.f);
#pragma unroll
  for (int dd = 0; dd < 16; ++dd) {
    const float qv = qh[dd];
    const float4 wv = *(const float4*)(Wb + (size_t)dd * E_DIM);
    a.x += qv * wv.x; a.y += qv * wv.y; a.z += qv * wv.z; a.w += qv * wv.w;
  }
  ps[dg][eg] = a;
  __syncthreads();
  if (t < 32) {
    float4 s = ps[0][t];
#pragma unroll
    for (int g = 1; g < 8; ++g) {
      const float4 b = ps[g][t];
      s.x += b.x; s.y += b.y; s.z += b.z; s.w += b.w;
    }
    const float sc = 0.08838834764831845f;   // 1/sqrt(128)
    s.x *= sc; s.y *= sc; s.z *= sc; s.w *= sc;
    *(float4*)(P_T + (size_t)h * E_DIM + ec * 128 + t * 4) = s;
  }
}

// ---------------- fused single-pass scores + softmax-weights + weighted-x ----------------
// wave w: head pair h0=2*(w&3),h0+1 ; row-half rh=w>>2 (4 rows of each 8-row tile).
__global__ __launch_bounds__(512, 2) void attn_fused5(
    const float* __restrict__ x,
    const float* __restrict__ P_T,       // [8][1024]
    float* __restrict__ partial_z,       // [nblk][8][1024]
    float* __restrict__ partial_sumw,    // [nblk][8]
    int rows_per_blk)
{
  __shared__ __align__(16) float sbuf[2][TILE_R][E_DIM];   // 64 KB x double-buffer; reused as z-stage [16][1024]
  __shared__ float swst[16];

  const int t    = threadIdx.x;
  const int wave = t >> 6;
  const int lane = t & 63;
  const int rh   = wave >> 2;          // row half
  const int h0   = (wave & 3) * 2;     // head pair base
  const size_t row0 = (size_t)blockIdx.x * rows_per_blk;
  const int ntiles  = rows_per_blk / TILE_R;

  // P fragments in registers: cols 4*(64k+lane)
  float4 p0[4], p1[4];
  {
    const float4* P0 = (const float4*)(P_T + (size_t)h0 * E_DIM);
    const float4* P1 = (const float4*)(P_T + (size_t)(h0 + 1) * E_DIM);
#pragma unroll
    for (int k = 0; k < 4; ++k) { p0[k] = P0[64 * k + lane]; p1[k] = P1[64 * k + lane]; }
  }

  float4 z0[4], z1[4];
#pragma unroll
  for (int k = 0; k < 4; ++k) {
    z0[k] = make_float4(0.f, 0.f, 0.f, 0.f);
    z1[k] = make_float4(0.f, 0.f, 0.f, 0.f);
  }
  float sumw0 = 0.f, sumw1 = 0.f;

  // prologue: stage tile 0 (wave stages row 'wave'; 4x 1KB wave-loads)
  {
    const float* g = x + (row0 + wave) * E_DIM + 4 * lane;
#pragma unroll
    for (int k = 0; k < 4; ++k) GLD16(g + k * 256, &sbuf[0][wave][k * 256]);
  }
  __syncthreads();   // drains vmcnt -> tile 0 resident

  for (int tile = 0; tile < ntiles; ++tile) {
    const int buf = tile & 1;

    // issue next tile's HBM->LDS loads first (in flight under this tile's compute)
    if (tile + 1 < ntiles) {
      const float* g = x + (row0 + (size_t)(tile + 1) * TILE_R + wave) * E_DIM + 4 * lane;
#pragma unroll
      for (int k = 0; k < 4; ++k) GLD16(g + k * 256, &sbuf[buf ^ 1][wave][k * 256]);
    }

#pragma unroll
    for (int rl = 0; rl < 4; ++rl) {
      const float4* xr4 = (const float4*)&sbuf[buf][rh * 4 + rl][0];
      float4 xr[4];
#pragma unroll
      for (int k = 0; k < 4; ++k) xr[k] = xr4[64 * k + lane];

      float s0 = 0.f, s1 = 0.f;
#pragma unroll
      for (int k = 0; k < 4; ++k) {
        s0 += xr[k].x * p0[k].x + xr[k].y * p0[k].y + xr[k].z * p0[k].z + xr[k].w * p0[k].w;
        s1 += xr[k].x * p1[k].x + xr[k].y * p1[k].y + xr[k].z * p1[k].z + xr[k].w * p1[k].w;
      }

      // packed 2-value 64-lane butterfly: even lanes end with sum(s0), odd with sum(s1)
      const bool odd = (lane & 1);
      float keep = odd ? s1 : s0;
      float oth  = odd ? s0 : s1;
      float ts = keep + __shfl_xor(oth, 1, 64);
      ts += __shfl_xor(ts, 2, 64);
      ts += __shfl_xor(ts, 4, 64);
      ts += __shfl_xor(ts, 8, 64);
      ts += __shfl_xor(ts, 16, 64);
      ts += __shfl_xor(ts, 32, 64);
      const float ex = __expf(ts);
      const float ox = __shfl_xor(ex, 1, 64);
      const float w0 = odd ? ox : ex;
      const float w1 = odd ? ex : ox;
      sumw0 += w0; sumw1 += w1;          // identical across lanes

#pragma unroll
      for (int k = 0; k < 4; ++k) {
        z0[k].x += w0 * xr[k].x; z0[k].y += w0 * xr[k].y;
        z0[k].z += w0 * xr[k].z; z0[k].w += w0 * xr[k].w;
        z1[k].x += w1 * xr[k].x; z1[k].y += w1 * xr[k].y;
        z1[k].z += w1 * xr[k].z; z1[k].w += w1 * xr[k].w;
      }
    }

    __syncthreads();   // all waves done with buf; next tile's loads drained
  }

  // intra-block combine of the two row-half partials, via LDS reuse.
  // slot layout: wave w writes z0->zs[2w], z1->zs[2w+1]  =>  head h lives in
  // slots h (rh=0 waves) and h+8 (rh=1 waves).
  float (*zs)[E_DIM] = (float(*)[E_DIM])&sbuf[0][0][0];
  {
    float4* zd0 = (float4*)&zs[2 * wave][0];
    float4* zd1 = (float4*)&zs[2 * wave + 1][0];
#pragma unroll
    for (int k = 0; k < 4; ++k) { zd0[64 * k + lane] = z0[k]; zd1[64 * k + lane] = z1[k]; }
  }
  if (lane == 0) { swst[2 * wave] = sumw0; swst[2 * wave + 1] = sumw1; }
  __syncthreads();

  {
    const float4* zsv = (const float4*)&zs[0][0];                        // [16][256]
    float4* pzb = (float4*)(partial_z + (size_t)blockIdx.x * (NHEAD * E_DIM));
#pragma unroll
    for (int j = 0; j < 4; ++j) {
      const int idx = t + 512 * j;                                       // 0..2047 = h*256+e4
      const float4 a = zsv[idx], b = zsv[idx + 2048];
      pzb[idx] = make_float4(a.x + b.x, a.y + b.y, a.z + b.z, a.w + b.w);
    }
  }
  if (t < NHEAD)
    partial_sumw[blockIdx.x * NHEAD + t] = swst[t] + swst[t + 8];
}

// ---------------- reduce partials: zn[h][e] = sum_b pz / sum_b psumw ----------------
__global__ __launch_bounds__(256) void reduce_z(
    const float* __restrict__ partial_z,
    const float* __restrict__ partial_sumw,
    float* __restrict__ zn, int nblk)
{
  __shared__ float red[256];
  __shared__ __align__(16) float swst[4][NHEAD];
  __shared__ float sumw_s[NHEAD];
  const int t = threadIdx.x;
  const int lane = t & 63, wave = t >> 6;

  float sw[NHEAD];
#pragma unroll
  for (int h = 0; h < NHEAD; ++h) sw[h] = 0.f;
  for (int b = t; b < nblk; b += 256) {
    const float4* p = (const float4*)(partial_sumw + (size_t)b * NHEAD);
    float4 a0 = p[0], a1 = p[1];
    sw[0] += a0.x; sw[1] += a0.y; sw[2] += a0.z; sw[3] += a0.w;
    sw[4] += a1.x; sw[5] += a1.y; sw[6] += a1.z; sw[7] += a1.w;
  }
#pragma unroll
  for (int m = 1; m < 64; m <<= 1) {
#pragma unroll
    for (int h = 0; h < NHEAD; ++h) sw[h] += __shfl_xor(sw[h], m, 64);
  }
  if (lane == 0) {
#pragma unroll
    for (int h = 0; h < NHEAD; ++h) swst[wave][h] = sw[h];
  }
  __syncthreads();
  if (t < NHEAD) sumw_s[t] = swst[0][t] + swst[1][t] + swst[2][t] + swst[3][t];

  const int o = blockIdx.x * 32 + (t & 31);
  const int g = t >> 5;
  float a = 0.f;
  for (int b = g; b < nblk; b += 8) a += partial_z[(size_t)b * (NHEAD * E_DIM) + o];
  red[t] = a;
  __syncthreads();
  if (t < 32) {
    float s2 = 0.f;
#pragma unroll
    for (int gg = 0; gg < 8; ++gg) s2 += red[gg * 32 + t];
    const int oo = blockIdx.x * 32 + t;
    zn[oo] = s2 / sumw_s[oo >> 10];   // oo = h*1024 + e
  }
}

// ---------------- attn[o] = Wv[o] . zn[h(o)] + bv[o] ----------------
__global__ __launch_bounds__(256) void proj_v(
    const float* __restrict__ W, const float* __restrict__ bias,
    const float* __restrict__ zn, float* __restrict__ attn)
{
  const int t = threadIdx.x, wave = t >> 6, lane = t & 63;
  const int o = blockIdx.x * 4 + wave;
  const float4* Wr = (const float4*)(W + ((size_t)2 * E_DIM + o) * E_DIM);
  const float4* zr = (const float4*)(zn + (size_t)(o >> 7) * E_DIM);
  float a = 0.f;
#pragma unroll
  for (int k = 0; k < 4; ++k) {
    float4 wv = Wr[lane + 64 * k];
    float4 zv = zr[lane + 64 * k];
    a += wv.x * zv.x + wv.y * zv.y + wv.z * zv.z + wv.w * zv.w;
  }
#pragma unroll
  for (int m = 1; m < 64; m <<= 1) a += __shfl_xor(a, m, 64);
  if (lane == 0) attn[o] = a + bias[2 * E_DIM + o];
}

// ---------------- out[e] = Wo[e] . attn + bo[e] ----------------
__global__ __launch_bounds__(256) void proj_o(
    const float* __restrict__ Wo, const float* __restrict__ bo,
    const float* __restrict__ attn, float* __restrict__ out)
{
  const int t = threadIdx.x, wave = t >> 6, lane = t & 63;
  const int o = blockIdx.x * 4 + wave;
  const float4* Wr = (const float4*)(Wo + (size_t)o * E_DIM);
  const float4* vr = (const float4*)attn;
  float a = 0.f;
#pragma unroll
  for (int k = 0; k < 4; ++k) {
    float4 wv = Wr[lane + 64 * k];
    float4 vv = vr[lane + 64 * k];
    a += wv.x * vv.x + wv.y * vv.y + wv.z * vv.z + wv.w * vv.w;
  }
#pragma unroll
  for (int m = 1; m < 64; m <<= 1) a += __shfl_xor(a, m, 64);
  if (lane == 0) out[o] = a + bo[o];
}

extern "C" void kernel_launch(void* const* d_in, const int* in_sizes, int n_in,
                              void* d_out, int out_size, void* d_ws, size_t ws_size,
                              hipStream_t stream)
{
  const float* x  = (const float*)d_in[0];   // [32768,1024]
  const float* Wi = (const float*)d_in[1];   // [3072,1024]
  const float* bi = (const float*)d_in[2];   // [3072]
  const float* Wo = (const float*)d_in[3];   // [1024,1024]
  const float* bo = (const float*)d_in[4];   // [1024]
  float* out = (float*)d_out;                // [1024] fp32

  // workspace layout (bytes)
  char* ws = (char*)d_ws;
  float* q     = (float*)(ws + 0);          // 1024 f
  float* P_T   = (float*)(ws + 4096);       // 8192 f
  float* zn    = (float*)(ws + 36864);      // 8192 f
  float* attn  = (float*)(ws + 69632);      // 1024 f
  float* psumw = (float*)(ws + 73728);      // nblk*8 f (<= 16 KB)
  const size_t pz_off = 90112;
  float* pz    = (float*)(ws + pz_off);     // nblk*8192 f

  // pick partial-block count from available workspace (constant across calls)
  int nblk = 128;
  if (ws_size >= pz_off + (size_t)512 * NHEAD * E_DIM * 4) nblk = 512;
  else if (ws_size >= pz_off + (size_t)256 * NHEAD * E_DIM * 4) nblk = 256;
  const int rows_per_blk = L_SEQ / nblk;

  proj_q     <<<256, 256, 0, stream>>>(Wi, bi, x, q);
  make_p     <<<dim3(8, 8), 256, 0, stream>>>(Wi, q, P_T);
  attn_fused5<<<nblk, 512, 0, stream>>>(x, P_T, pz, psumw, rows_per_blk);
  reduce_z   <<<256, 256, 0, stream>>>(pz, psumw, zn, nblk);
  proj_v     <<<256, 256, 0, stream>>>(Wi, bi, zn, attn);
  proj_o     <<<256, 256, 0, stream>>>(Wo, bo, attn, out);
}